// Round 4
// baseline (704.661 us; speedup 1.0000x reference)
//
#include <hip/hip_runtime.h>

#define N 8192
#define D 1024

typedef short bf16x8 __attribute__((ext_vector_type(8)));
typedef float f32x4 __attribute__((ext_vector_type(4)));
typedef unsigned short u16;

#define WAITV(n) asm volatile("s_waitcnt vmcnt(" #n ")" ::: "memory")
#define BAR() __builtin_amdgcn_s_barrier()

__device__ __forceinline__ u16 f2bf(float f) {
  unsigned u = __float_as_uint(f);
  u += 0x7FFF + ((u >> 16) & 1);   // RNE to bf16
  return (u16)(u >> 16);
}
__device__ __forceinline__ float bf2f(u16 h) {
  return __uint_as_float(((unsigned)h) << 16);
}

__device__ __forceinline__ void gload_lds16(const void* g, const void* l) {
  __builtin_amdgcn_global_load_lds(
      (const __attribute__((address_space(1))) void*)g,
      (__attribute__((address_space(3))) void*)l, 16, 0, 0);
}

// Swizzled [rows][32] bf16 tile, 64 B/row, 4x 16B chunks per row.
// Physical chunk = logical chunk ^ ((row>>1)&3). Involution applied on both
// the stage (global-source side) and the ds_read side.
__device__ __forceinline__ int swz_byte(int row, int logical_chunk) {
  return row * 64 + ((logical_chunk ^ ((row >> 1) & 3)) << 4);
}

// ---------------- K0: split X (fp32) into Hi/Lo bf16 ----------------
__global__ __launch_bounds__(256) void k_split(const float* __restrict__ X,
                                               u16* __restrict__ hi,
                                               u16* __restrict__ lo) {
  int i = blockIdx.x * 256 + threadIdx.x;   // float4 index, total N*D/4
  float4 x = ((const float4*)X)[i];
  u16 h0 = f2bf(x.x), h1 = f2bf(x.y), h2 = f2bf(x.z), h3 = f2bf(x.w);
  ushort4 hv = {h0, h1, h2, h3};
  ushort4 lv = {f2bf(x.x - bf2f(h0)), f2bf(x.y - bf2f(h1)),
                f2bf(x.z - bf2f(h2)), f2bf(x.w - bf2f(h3))};
  ((ushort4*)hi)[i] = hv;
  ((ushort4*)lo)[i] = lv;
}

// ---------------- K0b: transpose Xhi [N][D] -> XT [D][N] ----------------
__global__ __launch_bounds__(256) void k_transpose(const u16* __restrict__ Xh,
                                                   u16* __restrict__ XT) {
  __shared__ u16 t[32][33];
  const int jt = blockIdx.y * 32, dt = blockIdx.x * 32;
  const int c = threadIdx.x & 31, rg = threadIdx.x >> 5;   // rg in 0..7
#pragma unroll
  for (int k = 0; k < 4; ++k) {
    int r = rg * 4 + k;
    t[r][c] = Xh[(size_t)(jt + r) * D + dt + c];
  }
  __syncthreads();
#pragma unroll
  for (int k = 0; k < 4; ++k) {
    int d = rg * 4 + k;
    XT[(size_t)(dt + d) * N + jt + c] = t[c][d];
  }
}

// ------- K1: S = X X^T, symmetric: only upper-tri 128x128 blocks --------
// 2-deep global_load_lds pipeline, counted vmcnt, raw barriers.
__global__ __launch_bounds__(256) void k_qkt(const u16* __restrict__ Xh,
                                             const u16* __restrict__ Xl,
                                             float* __restrict__ S) {
  __shared__ union {
    u16 stage[2][4][128 * 32];   // 64 KiB: [buf][Ah,Al,Bh,Bl]
    float tbuf[128][64];         // transpose bounce (epilogue only)
  } sm;

  const int tid = threadIdx.x, wid = tid >> 6, lane = tid & 63;

  // XCD chunk swizzle over 2080 blocks (2080 = 8 * 260, bijective)
  int o = blockIdx.x;
  int l = (o & 7) * 260 + (o >> 3);
  // map linear id -> (bi, bj), bi <= bj, over 64x64 block grid
  int t = l, bi = 0;
  while (t >= 64 - bi) { t -= 64 - bi; ++bi; }
  const int bj = bi + t;
  const int brow = bi * 128, bcol = bj * 128;

  const int wr = wid >> 1, wc = wid & 1;
  const int fr = lane & 15;
  const int c0 = lane >> 4;          // logical 16B chunk for ds_read

  f32x4 acc[4][4] = {};

#define QKT_STAGE(kt, s) do {                                              \
    _Pragma("unroll")                                                      \
    for (int c = 0; c < 2; ++c) {                                          \
      int chunk = wid * 2 + c;                                             \
      int ebyte = chunk * 1024 + lane * 16;                                \
      int row = ebyte >> 6;                                                \
      int pc = (ebyte >> 4) & 3;                                           \
      int col = (pc ^ ((row >> 1) & 3)) * 8;                               \
      size_t ga = (size_t)(brow + row) * D + (kt) + col;                   \
      size_t gb = (size_t)(bcol + row) * D + (kt) + col;                   \
      gload_lds16(Xh + ga, (const char*)sm.stage[s][0] + ebyte);           \
      gload_lds16(Xl + ga, (const char*)sm.stage[s][1] + ebyte);           \
      gload_lds16(Xh + gb, (const char*)sm.stage[s][2] + ebyte);           \
      gload_lds16(Xl + gb, (const char*)sm.stage[s][3] + ebyte);           \
    }                                                                      \
  } while (0)

#define QKT_COMPUTE(s) do {                                                \
    bf16x8 ah[4], al[4], bh[4], bl[4];                                     \
    _Pragma("unroll")                                                      \
    for (int m = 0; m < 4; ++m) {                                          \
      int row = wr * 64 + m * 16 + fr;                                     \
      int pb = swz_byte(row, c0);                                          \
      ah[m] = *(const bf16x8*)((const char*)sm.stage[s][0] + pb);          \
      al[m] = *(const bf16x8*)((const char*)sm.stage[s][1] + pb);          \
    }                                                                      \
    _Pragma("unroll")                                                      \
    for (int n = 0; n < 4; ++n) {                                          \
      int row = wc * 64 + n * 16 + fr;                                     \
      int pb = swz_byte(row, c0);                                          \
      bh[n] = *(const bf16x8*)((const char*)sm.stage[s][2] + pb);          \
      bl[n] = *(const bf16x8*)((const char*)sm.stage[s][3] + pb);          \
    }                                                                      \
    _Pragma("unroll")                                                      \
    for (int m = 0; m < 4; ++m)                                            \
      _Pragma("unroll")                                                    \
      for (int n = 0; n < 4; ++n) {                                        \
        acc[m][n] = __builtin_amdgcn_mfma_f32_16x16x32_bf16(ah[m], bh[n], acc[m][n], 0, 0, 0); \
        acc[m][n] = __builtin_amdgcn_mfma_f32_16x16x32_bf16(ah[m], bl[n], acc[m][n], 0, 0, 0); \
        acc[m][n] = __builtin_amdgcn_mfma_f32_16x16x32_bf16(al[m], bh[n], acc[m][n], 0, 0, 0); \
      }                                                                    \
  } while (0)

  QKT_STAGE(0, 0);
  // main loop: 31 iters with next-tile prefetch; tile t lives in buf t&1
  for (int it = 0; it < 31; ++it) {
    QKT_STAGE((it + 1) * 32, (it + 1) & 1);
    WAITV(8);                       // tile it's 8 loads done; next 8 in flight
    BAR();
    QKT_COMPUTE(it & 1);
    asm volatile("s_waitcnt lgkmcnt(0)" ::: "memory");
    BAR();
  }
  // last iter (tile 31, buf 1), nothing in flight behind it
  WAITV(0);
  BAR();
  QKT_COMPUTE(1);

#undef QKT_STAGE
#undef QKT_COMPUTE

  const int rr = (lane >> 4) * 4;
  // direct tile write: S[brow..][bcol..]
#pragma unroll
  for (int m = 0; m < 4; ++m)
#pragma unroll
    for (int n = 0; n < 4; ++n)
#pragma unroll
      for (int r = 0; r < 4; ++r) {
        int row = brow + wr * 64 + m * 16 + rr + r;
        int col = bcol + wc * 64 + n * 16 + fr;
        S[(size_t)row * N + col] = acc[m][n][r];
      }

  // transposed tile write for off-diagonal blocks: S[bcol..][brow..]
  if (bi != bj) {
#pragma unroll
    for (int pass = 0; pass < 2; ++pass) {
      __syncthreads();                 // stage/tbuf reuse + prior reads done
      if (wr == pass) {
#pragma unroll
        for (int m = 0; m < 4; ++m)
#pragma unroll
          for (int n = 0; n < 4; ++n) {
            f32x4 v = acc[m][n];
            int c = wc * 64 + n * 16 + fr;
            int inner = ((m * 16 + rr) * 4) ^ ((c & 15) << 4);
            *(f32x4*)((char*)&sm.tbuf[c][0] + inner) = v;
          }
      }
      __syncthreads();
#pragma unroll
      for (int i = 0; i < 8; ++i) {
        int idx = i * 256 + tid;         // 2048 float4 = 128 cols x 16 quads
        int c = idx >> 4;                // 0..127
        int kq = idx & 15;               // 0..15
        int inner = (kq * 16) ^ ((c & 15) << 4);
        float4 v4 = *(const float4*)((const char*)&sm.tbuf[c][0] + inner);
        *(float4*)&S[(size_t)(bcol + c) * N + brow + pass * 64 + kq * 4] = v4;
      }
    }
  }
}

// ---------------- K2: in-place row softmax (+ optional bf16 P copy) -----
template <int WRITE_PB>
__global__ __launch_bounds__(256) void k_softmax(float* __restrict__ S,
                                                 u16* __restrict__ Pb) {
  const int row = blockIdx.x;
  float* p = S + (size_t)row * N;
  const int tid = threadIdx.x;
  const int wid = tid >> 6, lane = tid & 63;
  __shared__ float red[4];

  float4 v[8];
  float m = -INFINITY;
#pragma unroll
  for (int i = 0; i < 8; ++i) {
    int idx = i * 256 + tid;              // float4 index within row
    float4 x = ((const float4*)p)[idx];
    if ((row >> 2) == idx) ((float*)&x)[row & 3] = -INFINITY;  // exclude diag
    v[i] = x;
    m = fmaxf(m, fmaxf(fmaxf(x.x, x.y), fmaxf(x.z, x.w)));
  }
#pragma unroll
  for (int off = 32; off > 0; off >>= 1) m = fmaxf(m, __shfl_xor(m, off));
  if (lane == 0) red[wid] = m;
  __syncthreads();
  m = fmaxf(fmaxf(red[0], red[1]), fmaxf(red[2], red[3]));

  float s = 0.f;
#pragma unroll
  for (int i = 0; i < 8; ++i) {
    float4 e;
    e.x = __expf(v[i].x - m);
    e.y = __expf(v[i].y - m);
    e.z = __expf(v[i].z - m);
    e.w = __expf(v[i].w - m);
    v[i] = e;
    s += e.x + e.y + e.z + e.w;
  }
#pragma unroll
  for (int off = 32; off > 0; off >>= 1) s += __shfl_xor(s, off);
  __syncthreads();                        // red[] reuse
  if (lane == 0) red[wid] = s;
  __syncthreads();
  s = red[0] + red[1] + red[2] + red[3];
  float inv = 1.0f / s;
#pragma unroll
  for (int i = 0; i < 8; ++i) {
    int idx = i * 256 + tid;
    float4 x = v[i];
    x.x *= inv; x.y *= inv; x.z *= inv; x.w *= inv;
    ((float4*)p)[idx] = x;
    if (WRITE_PB) {
      ushort4 h = {f2bf(x.x), f2bf(x.y), f2bf(x.z), f2bf(x.w)};
      ((ushort4*)(Pb + (size_t)row * N))[idx] = h;
    }
  }
}

// -------- K3: out = P @ X, bf16 Pb path. BM=128, BN=256, 512 thr --------
// 3-deep global_load_lds pipeline, counted vmcnt, raw barriers.
__global__ __launch_bounds__(512) void k_pv(const u16* __restrict__ Pb,
                                            const u16* __restrict__ XT,
                                            float* __restrict__ Out) {
  __shared__ u16 As[3][128 * 32];   // 24 KiB
  __shared__ u16 Bs[3][256 * 32];   // 48 KiB
  const int tid = threadIdx.x, wid = tid >> 6, lane = tid & 63;

  // XCD chunk swizzle over 256 blocks (q=32, bijective): blocks sharing a
  // Pb row-panel (and neighbors) land on one XCD.
  int o = blockIdx.y * 4 + blockIdx.x;
  int l = (o & 7) * 32 + (o >> 3);
  const int brow = (l >> 2) * 128;     // rows of P / out
  const int bcol = (l & 3) * 256;      // cols of out (d)

  const int wr = wid >> 2, wc = wid & 3;   // 2 x 4 wave grid, 64x64 each
  const int fr = lane & 15;
  const int c0 = lane >> 4;

  f32x4 acc[4][4] = {};

#define PV_STAGE(kt, s) do {                                               \
    _Pragma("unroll")                                                      \
    for (int c = 0; c < 2; ++c) {                                          \
      int chunk = wid * 2 + c;                                             \
      int ebyte = chunk * 1024 + lane * 16;                                \
      int row = ebyte >> 6;                                                \
      int pc = (ebyte >> 4) & 3;                                           \
      int col = (pc ^ ((row >> 1) & 3)) * 8;                               \
      gload_lds16(XT + (size_t)(bcol + row) * N + (kt) + col,              \
                  (const char*)Bs[s] + ebyte);                             \
    }                                                                      \
    {                                                                      \
      int ebyte = wid * 1024 + lane * 16;                                  \
      int row = ebyte >> 6;                                                \
      int pc = (ebyte >> 4) & 3;                                           \
      int col = (pc ^ ((row >> 1) & 3)) * 8;                               \
      gload_lds16(Pb + (size_t)(brow + row) * N + (kt) + col,              \
                  (const char*)As[s] + ebyte);                             \
    }                                                                      \
  } while (0)

#define PV_COMPUTE(s) do {                                                 \
    bf16x8 a[4], b[4];                                                     \
    _Pragma("unroll")                                                      \
    for (int m = 0; m < 4; ++m) {                                          \
      int row = wr * 64 + m * 16 + fr;                                     \
      a[m] = *(const bf16x8*)((const char*)As[s] + swz_byte(row, c0));     \
    }                                                                      \
    _Pragma("unroll")                                                      \
    for (int n = 0; n < 4; ++n) {                                          \
      int row = wc * 64 + n * 16 + fr;                                     \
      b[n] = *(const bf16x8*)((const char*)Bs[s] + swz_byte(row, c0));     \
    }                                                                      \
    _Pragma("unroll")                                                      \
    for (int m = 0; m < 4; ++m)                                            \
      _Pragma("unroll")                                                    \
      for (int n = 0; n < 4; ++n)                                          \
        acc[m][n] = __builtin_amdgcn_mfma_f32_16x16x32_bf16(a[m], b[n], acc[m][n], 0, 0, 0); \
  } while (0)

  PV_STAGE(0, 0);
  PV_STAGE(32, 1);
  PV_STAGE(64, 2);
  int s = 0;
  for (int it = 0; it < 254; ++it) {
    WAITV(6);                    // tile it's 3 loads done; 6 still in flight
    BAR();
    PV_COMPUTE(s);
    asm volatile("s_waitcnt lgkmcnt(0)" ::: "memory");
    BAR();
    if (it + 3 < 256) PV_STAGE((it + 3) * 32, s);
    s = (s == 2) ? 0 : s + 1;
  }
  WAITV(3);                      // tile 254 done; tile 255 in flight
  BAR();
  PV_COMPUTE(s);
  asm volatile("s_waitcnt lgkmcnt(0)" ::: "memory");
  BAR();
  s = (s == 2) ? 0 : s + 1;
  WAITV(0);                      // tile 255 done
  BAR();
  PV_COMPUTE(s);

#undef PV_STAGE
#undef PV_COMPUTE

  const int rr = (lane >> 4) * 4;
#pragma unroll
  for (int m = 0; m < 4; ++m)
#pragma unroll
    for (int n = 0; n < 4; ++n)
#pragma unroll
      for (int r = 0; r < 4; ++r) {
        int row = brow + wr * 64 + m * 16 + rr + r;
        int col = bcol + wc * 64 + n * 16 + fr;
        Out[(size_t)row * D + col] = acc[m][n][r];
      }
}

// -------- K3 fallback: out = P @ X from fp32 P (no Pb workspace) --------
__global__ __launch_bounds__(512) void k_pv_f32(const float* __restrict__ P,
                                                const u16* __restrict__ XT,
                                                float* __restrict__ Out) {
  __shared__ u16 As[128 * 32];
  __shared__ u16 Bs[256 * 32];
  const int tid = threadIdx.x, wid = tid >> 6, lane = tid & 63;
  const int brow = blockIdx.y * 128;
  const int bcol = blockIdx.x * 256;
  const int wr = wid >> 2, wc = wid & 3;
  const int fr = lane & 15;
  const int c0 = lane >> 4;

  f32x4 acc[4][4] = {};

  for (int kt = 0; kt < N; kt += 32) {
    __syncthreads();
#pragma unroll
    for (int c = 0; c < 2; ++c) {
      int chunk = wid * 2 + c;
      int ebyte = chunk * 1024 + lane * 16;
      int row = ebyte >> 6;
      int pc = (ebyte >> 4) & 3;
      int col = (pc ^ ((row >> 1) & 3)) * 8;
      gload_lds16(XT + (size_t)(bcol + row) * N + kt + col, (const char*)Bs + ebyte);
    }
#pragma unroll
    for (int i = 0; i < 2; ++i) {
      int idx = i * 512 + tid;
      int e = idx * 4;
      int row = e >> 5, col = e & 31;
      float4 x = *(const float4*)(P + (size_t)(brow + row) * N + kt + col);
      ushort4 h = {f2bf(x.x), f2bf(x.y), f2bf(x.z), f2bf(x.w)};
      int inner = (col * 2) ^ (((row >> 1) & 3) << 4);
      *(ushort4*)((char*)As + row * 64 + inner) = h;
    }
    __syncthreads();

    bf16x8 a[4], b[4];
#pragma unroll
    for (int m = 0; m < 4; ++m) {
      int row = wr * 64 + m * 16 + fr;
      a[m] = *(const bf16x8*)((const char*)As + swz_byte(row, c0));
    }
#pragma unroll
    for (int n = 0; n < 4; ++n) {
      int row = wc * 64 + n * 16 + fr;
      b[n] = *(const bf16x8*)((const char*)Bs + swz_byte(row, c0));
    }
#pragma unroll
    for (int m = 0; m < 4; ++m)
#pragma unroll
      for (int n = 0; n < 4; ++n)
        acc[m][n] = __builtin_amdgcn_mfma_f32_16x16x32_bf16(a[m], b[n], acc[m][n], 0, 0, 0);
  }

  const int rr = (lane >> 4) * 4;
#pragma unroll
  for (int m = 0; m < 4; ++m)
#pragma unroll
    for (int n = 0; n < 4; ++n)
#pragma unroll
      for (int r = 0; r < 4; ++r) {
        int row = brow + wr * 64 + m * 16 + rr + r;
        int col = bcol + wc * 64 + n * 16 + fr;
        Out[(size_t)row * D + col] = acc[m][n][r];
      }
}

extern "C" void kernel_launch(void* const* d_in, const int* in_sizes, int n_in,
                              void* d_out, int out_size, void* d_ws, size_t ws_size,
                              hipStream_t stream) {
  const float* X = (const float*)d_in[0];
  float* out = (float*)d_out;
  float* attn = out + (size_t)N * D;        // second output: raw S, then softmaxed

  u16* Xh = (u16*)d_ws;                     // 16 MB
  u16* Xl = Xh + (size_t)N * D;             // 16 MB
  u16* XT = Xl + (size_t)N * D;             // 16 MB
  u16* Pb = XT + (size_t)N * D;             // 128 MB (optional)
  const bool usePb =
      ws_size >= ((size_t)N * D * 3 + (size_t)N * N) * sizeof(u16);

  k_split<<<(N * D / 4) / 256, 256, 0, stream>>>(X, Xh, Xl);
  k_transpose<<<dim3(D / 32, N / 32), 256, 0, stream>>>(Xh, XT);
  k_qkt<<<64 * 65 / 2, 256, 0, stream>>>(Xh, Xl, attn);
  if (usePb) {
    k_softmax<1><<<N, 256, 0, stream>>>(attn, Pb);
    k_pv<<<dim3(D / 256, N / 128), 512, 0, stream>>>(Pb, XT, out);
  } else {
    k_softmax<0><<<N, 256, 0, stream>>>(attn, nullptr);
    k_pv_f32<<<dim3(D / 256, N / 128), 512, 0, stream>>>(attn, XT, out);
  }
}

// Round 5
// 618.638 us; speedup vs baseline: 1.1391x; 1.1391x over previous
//
#include <hip/hip_runtime.h>

#define N 8192
#define D 1024

typedef short bf16x8 __attribute__((ext_vector_type(8)));
typedef float f32x4 __attribute__((ext_vector_type(4)));
typedef unsigned short u16;

#define WAITV(n) asm volatile("s_waitcnt vmcnt(" #n ")" ::: "memory")
#define BAR() __builtin_amdgcn_s_barrier()

__device__ __forceinline__ u16 f2bf(float f) {
  unsigned u = __float_as_uint(f);
  u += 0x7FFF + ((u >> 16) & 1);   // RNE to bf16
  return (u16)(u >> 16);
}
__device__ __forceinline__ float bf2f(u16 h) {
  return __uint_as_float(((unsigned)h) << 16);
}

__device__ __forceinline__ void gload_lds16(const void* g, const void* l) {
  __builtin_amdgcn_global_load_lds(
      (const __attribute__((address_space(1))) void*)g,
      (__attribute__((address_space(3))) void*)l, 16, 0, 0);
}

// Swizzled [rows][32] bf16 tile, 64 B/row, 4x 16B chunks per row.
// Physical chunk = logical chunk ^ ((row>>1)&3). Involution applied on both
// the stage (global-source side) and the ds_read side.
__device__ __forceinline__ int swz_byte(int row, int logical_chunk) {
  return row * 64 + ((logical_chunk ^ ((row >> 1) & 3)) << 4);
}

// ---------------- K0: split X (fp32) into Hi/Lo bf16 ----------------
__global__ __launch_bounds__(256) void k_split(const float* __restrict__ X,
                                               u16* __restrict__ hi,
                                               u16* __restrict__ lo) {
  int i = blockIdx.x * 256 + threadIdx.x;   // float4 index, total N*D/4
  float4 x = ((const float4*)X)[i];
  u16 h0 = f2bf(x.x), h1 = f2bf(x.y), h2 = f2bf(x.z), h3 = f2bf(x.w);
  ushort4 hv = {h0, h1, h2, h3};
  ushort4 lv = {f2bf(x.x - bf2f(h0)), f2bf(x.y - bf2f(h1)),
                f2bf(x.z - bf2f(h2)), f2bf(x.w - bf2f(h3))};
  ((ushort4*)hi)[i] = hv;
  ((ushort4*)lo)[i] = lv;
}

// ---------------- K0b: transpose Xhi [N][D] -> XT [D][N] ----------------
__global__ __launch_bounds__(256) void k_transpose(const u16* __restrict__ Xh,
                                                   u16* __restrict__ XT) {
  __shared__ u16 t[32][33];
  const int jt = blockIdx.y * 32, dt = blockIdx.x * 32;
  const int c = threadIdx.x & 31, rg = threadIdx.x >> 5;   // rg in 0..7
#pragma unroll
  for (int k = 0; k < 4; ++k) {
    int r = rg * 4 + k;
    t[r][c] = Xh[(size_t)(jt + r) * D + dt + c];
  }
  __syncthreads();
#pragma unroll
  for (int k = 0; k < 4; ++k) {
    int d = rg * 4 + k;
    XT[(size_t)(dt + d) * N + jt + c] = t[c][d];
  }
}

// ------- K1: S = X X^T, symmetric: only upper-tri 128x128 blocks --------
// Serialized stage->sync->compute (no DMA/ds_read overlap: 8 DMA streams/wave
// overlapping reads caused a 1e8 bank-conflict storm in R4). XCD swizzle.
__global__ __launch_bounds__(256) void k_qkt(const u16* __restrict__ Xh,
                                             const u16* __restrict__ Xl,
                                             float* __restrict__ S) {
  __shared__ union {
    u16 stage[4][128 * 32];     // Ah, Al, Bh, Bl  (32 KiB)
    float tbuf[128][64];        // transpose bounce (32 KiB, XOR-swizzled)
  } sm;
  u16* Ah = sm.stage[0];
  u16* Al = sm.stage[1];
  u16* Bh = sm.stage[2];
  u16* Bl = sm.stage[3];

  const int tid = threadIdx.x, wid = tid >> 6, lane = tid & 63;

  // XCD chunk swizzle over 2080 blocks (2080 = 8 * 260, bijective):
  // XCD x gets a contiguous band of the triangle -> A row-panels L2-local.
  int o = blockIdx.x;
  int l = (o & 7) * 260 + (o >> 3);
  // map linear id -> (bi, bj), bi <= bj, over 64x64 block grid
  int t = l, bi = 0;
  while (t >= 64 - bi) { t -= 64 - bi; ++bi; }
  const int bj = bi + t;
  const int brow = bi * 128, bcol = bj * 128;

  const int wr = wid >> 1, wc = wid & 1;
  const int fr = lane & 15;
  const int c0 = lane >> 4;          // logical 16B chunk for ds_read

  f32x4 acc[4][4] = {};

  for (int kt = 0; kt < D; kt += 32) {
    __syncthreads();
#pragma unroll
    for (int c = 0; c < 2; ++c) {
      int chunk = wid * 2 + c;               // 0..7 (1024B chunks)
      int ebyte = chunk * 1024 + lane * 16;  // linear LDS dest byte
      int row = ebyte >> 6;
      int pc = (ebyte >> 4) & 3;             // physical chunk slot
      int col = (pc ^ ((row >> 1) & 3)) * 8; // logical col staged there
      size_t ga = (size_t)(brow + row) * D + kt + col;
      size_t gb = (size_t)(bcol + row) * D + kt + col;
      gload_lds16(Xh + ga, (const char*)Ah + ebyte);
      gload_lds16(Xl + ga, (const char*)Al + ebyte);
      gload_lds16(Xh + gb, (const char*)Bh + ebyte);
      gload_lds16(Xl + gb, (const char*)Bl + ebyte);
    }
    __syncthreads();

    bf16x8 ah[4], al[4], bh[4], bl[4];
#pragma unroll
    for (int m = 0; m < 4; ++m) {
      int row = wr * 64 + m * 16 + fr;
      int pb = swz_byte(row, c0);
      ah[m] = *(const bf16x8*)((const char*)Ah + pb);
      al[m] = *(const bf16x8*)((const char*)Al + pb);
    }
#pragma unroll
    for (int n = 0; n < 4; ++n) {
      int row = wc * 64 + n * 16 + fr;
      int pb = swz_byte(row, c0);
      bh[n] = *(const bf16x8*)((const char*)Bh + pb);
      bl[n] = *(const bf16x8*)((const char*)Bl + pb);
    }
#pragma unroll
    for (int m = 0; m < 4; ++m)
#pragma unroll
      for (int n = 0; n < 4; ++n) {
        acc[m][n] = __builtin_amdgcn_mfma_f32_16x16x32_bf16(ah[m], bh[n], acc[m][n], 0, 0, 0);
        acc[m][n] = __builtin_amdgcn_mfma_f32_16x16x32_bf16(ah[m], bl[n], acc[m][n], 0, 0, 0);
        acc[m][n] = __builtin_amdgcn_mfma_f32_16x16x32_bf16(al[m], bh[n], acc[m][n], 0, 0, 0);
      }
  }

  const int rr = (lane >> 4) * 4;
  // direct tile write: S[brow..][bcol..]
#pragma unroll
  for (int m = 0; m < 4; ++m)
#pragma unroll
    for (int n = 0; n < 4; ++n)
#pragma unroll
      for (int r = 0; r < 4; ++r) {
        int row = brow + wr * 64 + m * 16 + rr + r;
        int col = bcol + wc * 64 + n * 16 + fr;
        S[(size_t)row * N + col] = acc[m][n][r];
      }

  // transposed tile write for off-diagonal blocks: S[bcol..][brow..]
  if (bi != bj) {
#pragma unroll
    for (int pass = 0; pass < 2; ++pass) {
      __syncthreads();                 // stage/tbuf reuse + prior reads done
      if (wr == pass) {
#pragma unroll
        for (int m = 0; m < 4; ++m)
#pragma unroll
          for (int n = 0; n < 4; ++n) {
            f32x4 v = acc[m][n];
            int c = wc * 64 + n * 16 + fr;
            int inner = ((m * 16 + rr) * 4) ^ ((c & 15) << 4);
            *(f32x4*)((char*)&sm.tbuf[c][0] + inner) = v;
          }
      }
      __syncthreads();
#pragma unroll
      for (int i = 0; i < 8; ++i) {
        int idx = i * 256 + tid;         // 2048 float4 = 128 cols x 16 quads
        int c = idx >> 4;                // 0..127
        int kq = idx & 15;               // 0..15
        int inner = (kq * 16) ^ ((c & 15) << 4);
        float4 v4 = *(const float4*)((const char*)&sm.tbuf[c][0] + inner);
        *(float4*)&S[(size_t)(bcol + c) * N + brow + pass * 64 + kq * 4] = v4;
      }
    }
  }
}

// ---------------- K2: in-place row softmax (+ optional bf16 P copy) -----
template <int WRITE_PB>
__global__ __launch_bounds__(256) void k_softmax(float* __restrict__ S,
                                                 u16* __restrict__ Pb) {
  const int row = blockIdx.x;
  float* p = S + (size_t)row * N;
  const int tid = threadIdx.x;
  const int wid = tid >> 6, lane = tid & 63;
  __shared__ float red[4];

  float4 v[8];
  float m = -INFINITY;
#pragma unroll
  for (int i = 0; i < 8; ++i) {
    int idx = i * 256 + tid;              // float4 index within row
    float4 x = ((const float4*)p)[idx];
    if ((row >> 2) == idx) ((float*)&x)[row & 3] = -INFINITY;  // exclude diag
    v[i] = x;
    m = fmaxf(m, fmaxf(fmaxf(x.x, x.y), fmaxf(x.z, x.w)));
  }
#pragma unroll
  for (int off = 32; off > 0; off >>= 1) m = fmaxf(m, __shfl_xor(m, off));
  if (lane == 0) red[wid] = m;
  __syncthreads();
  m = fmaxf(fmaxf(red[0], red[1]), fmaxf(red[2], red[3]));

  float s = 0.f;
#pragma unroll
  for (int i = 0; i < 8; ++i) {
    float4 e;
    e.x = __expf(v[i].x - m);
    e.y = __expf(v[i].y - m);
    e.z = __expf(v[i].z - m);
    e.w = __expf(v[i].w - m);
    v[i] = e;
    s += e.x + e.y + e.z + e.w;
  }
#pragma unroll
  for (int off = 32; off > 0; off >>= 1) s += __shfl_xor(s, off);
  __syncthreads();                        // red[] reuse
  if (lane == 0) red[wid] = s;
  __syncthreads();
  s = red[0] + red[1] + red[2] + red[3];
  float inv = 1.0f / s;
#pragma unroll
  for (int i = 0; i < 8; ++i) {
    int idx = i * 256 + tid;
    float4 x = v[i];
    x.x *= inv; x.y *= inv; x.z *= inv; x.w *= inv;
    ((float4*)p)[idx] = x;
    if (WRITE_PB) {
      ushort4 h = {f2bf(x.x), f2bf(x.y), f2bf(x.z), f2bf(x.w)};
      ((ushort4*)(Pb + (size_t)row * N))[idx] = h;
    }
  }
}

// -------- K3: out = P @ X, bf16 Pb path. BM=128, BN=256, 512 thr --------
// 3-deep global_load_lds pipeline, counted vmcnt, raw barriers. (R4-proven.)
__global__ __launch_bounds__(512) void k_pv(const u16* __restrict__ Pb,
                                            const u16* __restrict__ XT,
                                            float* __restrict__ Out) {
  __shared__ u16 As[3][128 * 32];   // 24 KiB
  __shared__ u16 Bs[3][256 * 32];   // 48 KiB
  const int tid = threadIdx.x, wid = tid >> 6, lane = tid & 63;

  // XCD chunk swizzle over 256 blocks (q=32, bijective)
  int o = blockIdx.y * 4 + blockIdx.x;
  int l = (o & 7) * 32 + (o >> 3);
  const int brow = (l >> 2) * 128;     // rows of P / out
  const int bcol = (l & 3) * 256;      // cols of out (d)

  const int wr = wid >> 2, wc = wid & 3;   // 2 x 4 wave grid, 64x64 each
  const int fr = lane & 15;
  const int c0 = lane >> 4;

  f32x4 acc[4][4] = {};

#define PV_STAGE(kt, s) do {                                               \
    _Pragma("unroll")                                                      \
    for (int c = 0; c < 2; ++c) {                                          \
      int chunk = wid * 2 + c;                                             \
      int ebyte = chunk * 1024 + lane * 16;                                \
      int row = ebyte >> 6;                                                \
      int pc = (ebyte >> 4) & 3;                                           \
      int col = (pc ^ ((row >> 1) & 3)) * 8;                               \
      gload_lds16(XT + (size_t)(bcol + row) * N + (kt) + col,              \
                  (const char*)Bs[s] + ebyte);                             \
    }                                                                      \
    {                                                                      \
      int ebyte = wid * 1024 + lane * 16;                                  \
      int row = ebyte >> 6;                                                \
      int pc = (ebyte >> 4) & 3;                                           \
      int col = (pc ^ ((row >> 1) & 3)) * 8;                               \
      gload_lds16(Pb + (size_t)(brow + row) * N + (kt) + col,              \
                  (const char*)As[s] + ebyte);                             \
    }                                                                      \
  } while (0)

#define PV_COMPUTE(s) do {                                                 \
    bf16x8 a[4], b[4];                                                     \
    _Pragma("unroll")                                                      \
    for (int m = 0; m < 4; ++m) {                                          \
      int row = wr * 64 + m * 16 + fr;                                     \
      a[m] = *(const bf16x8*)((const char*)As[s] + swz_byte(row, c0));     \
    }                                                                      \
    _Pragma("unroll")                                                      \
    for (int n = 0; n < 4; ++n) {                                          \
      int row = wc * 64 + n * 16 + fr;                                     \
      b[n] = *(const bf16x8*)((const char*)Bs[s] + swz_byte(row, c0));     \
    }                                                                      \
    _Pragma("unroll")                                                      \
    for (int m = 0; m < 4; ++m)                                            \
      _Pragma("unroll")                                                    \
      for (int n = 0; n < 4; ++n)                                          \
        acc[m][n] = __builtin_amdgcn_mfma_f32_16x16x32_bf16(a[m], b[n], acc[m][n], 0, 0, 0); \
  } while (0)

  PV_STAGE(0, 0);
  PV_STAGE(32, 1);
  PV_STAGE(64, 2);
  int s = 0;
  for (int it = 0; it < 254; ++it) {
    WAITV(6);                    // tile it's 3 loads done; 6 still in flight
    BAR();
    PV_COMPUTE(s);
    asm volatile("s_waitcnt lgkmcnt(0)" ::: "memory");
    BAR();
    if (it + 3 < 256) PV_STAGE((it + 3) * 32, s);
    s = (s == 2) ? 0 : s + 1;
  }
  WAITV(3);                      // tile 254 done; tile 255 in flight
  BAR();
  PV_COMPUTE(s);
  asm volatile("s_waitcnt lgkmcnt(0)" ::: "memory");
  BAR();
  s = (s == 2) ? 0 : s + 1;
  WAITV(0);                      // tile 255 done
  BAR();
  PV_COMPUTE(s);

#undef PV_STAGE
#undef PV_COMPUTE

  const int rr = (lane >> 4) * 4;
#pragma unroll
  for (int m = 0; m < 4; ++m)
#pragma unroll
    for (int n = 0; n < 4; ++n)
#pragma unroll
      for (int r = 0; r < 4; ++r) {
        int row = brow + wr * 64 + m * 16 + rr + r;
        int col = bcol + wc * 64 + n * 16 + fr;
        Out[(size_t)row * D + col] = acc[m][n][r];
      }
}

// -------- K3 fallback: out = P @ X from fp32 P (no Pb workspace) --------
__global__ __launch_bounds__(512) void k_pv_f32(const float* __restrict__ P,
                                                const u16* __restrict__ XT,
                                                float* __restrict__ Out) {
  __shared__ u16 As[128 * 32];
  __shared__ u16 Bs[256 * 32];
  const int tid = threadIdx.x, wid = tid >> 6, lane = tid & 63;
  const int brow = blockIdx.y * 128;
  const int bcol = blockIdx.x * 256;
  const int wr = wid >> 2, wc = wid & 3;
  const int fr = lane & 15;
  const int c0 = lane >> 4;

  f32x4 acc[4][4] = {};

  for (int kt = 0; kt < N; kt += 32) {
    __syncthreads();
#pragma unroll
    for (int c = 0; c < 2; ++c) {
      int chunk = wid * 2 + c;
      int ebyte = chunk * 1024 + lane * 16;
      int row = ebyte >> 6;
      int pc = (ebyte >> 4) & 3;
      int col = (pc ^ ((row >> 1) & 3)) * 8;
      gload_lds16(XT + (size_t)(bcol + row) * N + kt + col, (const char*)Bs + ebyte);
    }
#pragma unroll
    for (int i = 0; i < 2; ++i) {
      int idx = i * 512 + tid;
      int e = idx * 4;
      int row = e >> 5, col = e & 31;
      float4 x = *(const float4*)(P + (size_t)(brow + row) * N + kt + col);
      ushort4 h = {f2bf(x.x), f2bf(x.y), f2bf(x.z), f2bf(x.w)};
      int inner = (col * 2) ^ (((row >> 1) & 3) << 4);
      *(ushort4*)((char*)As + row * 64 + inner) = h;
    }
    __syncthreads();

    bf16x8 a[4], b[4];
#pragma unroll
    for (int m = 0; m < 4; ++m) {
      int row = wr * 64 + m * 16 + fr;
      a[m] = *(const bf16x8*)((const char*)As + swz_byte(row, c0));
    }
#pragma unroll
    for (int n = 0; n < 4; ++n) {
      int row = wc * 64 + n * 16 + fr;
      b[n] = *(const bf16x8*)((const char*)Bs + swz_byte(row, c0));
    }
#pragma unroll
    for (int m = 0; m < 4; ++m)
#pragma unroll
      for (int n = 0; n < 4; ++n)
        acc[m][n] = __builtin_amdgcn_mfma_f32_16x16x32_bf16(a[m], b[n], acc[m][n], 0, 0, 0);
  }

  const int rr = (lane >> 4) * 4;
#pragma unroll
  for (int m = 0; m < 4; ++m)
#pragma unroll
    for (int n = 0; n < 4; ++n)
#pragma unroll
      for (int r = 0; r < 4; ++r) {
        int row = brow + wr * 64 + m * 16 + rr + r;
        int col = bcol + wc * 64 + n * 16 + fr;
        Out[(size_t)row * D + col] = acc[m][n][r];
      }
}

extern "C" void kernel_launch(void* const* d_in, const int* in_sizes, int n_in,
                              void* d_out, int out_size, void* d_ws, size_t ws_size,
                              hipStream_t stream) {
  const float* X = (const float*)d_in[0];
  float* out = (float*)d_out;
  float* attn = out + (size_t)N * D;        // second output: raw S, then softmaxed

  u16* Xh = (u16*)d_ws;                     // 16 MB
  u16* Xl = Xh + (size_t)N * D;             // 16 MB
  u16* XT = Xl + (size_t)N * D;             // 16 MB
  u16* Pb = XT + (size_t)N * D;             // 128 MB (optional)
  const bool usePb =
      ws_size >= ((size_t)N * D * 3 + (size_t)N * N) * sizeof(u16);

  k_split<<<(N * D / 4) / 256, 256, 0, stream>>>(X, Xh, Xl);
  k_transpose<<<dim3(D / 32, N / 32), 256, 0, stream>>>(Xh, XT);
  k_qkt<<<64 * 65 / 2, 256, 0, stream>>>(Xh, Xl, attn);
  if (usePb) {
    k_softmax<1><<<N, 256, 0, stream>>>(attn, Pb);
    k_pv<<<dim3(D / 256, N / 128), 512, 0, stream>>>(Pb, XT, out);
  } else {
    k_softmax<0><<<N, 256, 0, stream>>>(attn, nullptr);
    k_pv_f32<<<dim3(D / 256, N / 128), 512, 0, stream>>>(attn, XT, out);
  }
}